// Round 10
// baseline (99.094 us; speedup 1.0000x reference)
//
#include <hip/hip_runtime.h>
#include <math.h>

#define EPSQ 1e-8f
#define LOG2E 1.4426950408889634f

typedef float f2 __attribute__((ext_vector_type(2)));
typedef float f4 __attribute__((ext_vector_type(4)));

__device__ __forceinline__ float rcp_fast(float x) { return __builtin_amdgcn_rcpf(x); }
__device__ __forceinline__ float rsq_fast(float x) { return __builtin_amdgcn_rsqf(x); }
__device__ __forceinline__ f2 pk_fma(f2 a, f2 b, f2 c) { return __builtin_elementwise_fma(a, b, c); }

// DPP cross-lane move: ctrl must be a compile-time constant.
#define DPP_F(x, ctrl) \
    __int_as_float(__builtin_amdgcn_update_dpp(0, __float_as_int(x), (ctrl), 0xF, 0xF, true))

// All-reduce sum within each aligned 16-lane group (pure VALU, no LDS).
__device__ __forceinline__ float allsum16(float v) {
    v += DPP_F(v, 0xB1);   // quad_perm [1,0,3,2]  == xor 1
    v += DPP_F(v, 0x4E);   // quad_perm [2,3,0,1]  == xor 2
    v += DPP_F(v, 0x124);  // row_ror:4
    v += DPP_F(v, 0x128);  // row_ror:8
    return v;
}

// Hamilton product (q * x) + t as EXACTLY 8 v_pk_fma_f32 (proven clean in R9).
__device__ __forceinline__ void hamilton_pk(f2 q01, f2 q23, f2 p01, f2 p23,
                                            f2 ta, f2 tb, f2& a, f2& b2) {
    asm("v_pk_fma_f32 %0, %2, %3, %4 op_sel:[0,0,0] op_sel_hi:[0,1,1]\n\t"
        "v_pk_fma_f32 %0, %2, %3, %0 op_sel:[1,1,0] op_sel_hi:[1,0,1] neg_lo:[1,0,0]\n\t"
        "v_pk_fma_f32 %0, %5, %6, %0 op_sel:[0,0,0] op_sel_hi:[0,1,1] neg_lo:[1,0,0]\n\t"
        "v_pk_fma_f32 %0, %5, %6, %0 op_sel:[1,1,0] op_sel_hi:[1,0,1] neg_lo:[1,0,0] neg_hi:[1,0,0]\n\t"
        "v_pk_fma_f32 %1, %2, %6, %7 op_sel:[0,0,0] op_sel_hi:[0,1,1]\n\t"
        "v_pk_fma_f32 %1, %2, %6, %1 op_sel:[1,1,0] op_sel_hi:[1,0,1] neg_lo:[1,0,0]\n\t"
        "v_pk_fma_f32 %1, %5, %3, %1 op_sel:[0,0,0] op_sel_hi:[0,1,1] neg_hi:[1,0,0]\n\t"
        "v_pk_fma_f32 %1, %5, %3, %1 op_sel:[1,1,0] op_sel_hi:[1,0,1]"
        : "=&v"(a), "=&v"(b2)
        : "v"(q01), "v"(p01), "v"(ta), "v"(q23), "v"(p23), "v"(tb));
}

// One thread per (sample n, output capsule o). Block = 256 = 16 samples x 16 o.
// tid = ln*16 + o (o in low 4 bits): softmax-over-o lives in one 16-lane DPP row.
__global__ __launch_bounds__(256, 4) void caps_kernel(
    const float* __restrict__ x,      // [N,16,4]
    const float* __restrict__ quats,  // [16,16,4]
    const float* __restrict__ scale,  // [16,16,1]
    const float* __restrict__ trans,  // [16,16,3]
    const float* __restrict__ bias,   // [16]
    const float* __restrict__ beta,   // [16]
    const float* __restrict__ alpha,  // [16]
    float* __restrict__ out)          // [N,16,4]
{
    __shared__ __align__(16) float qs[16][16][4];  // folded scale * qn  [i][o][4]
    __shared__ __align__(16) float tr[16][16][4];  // (0, tx, ty, tz)    [i][o][4]
    __shared__ __align__(16) float xs[16][68];     // x tile, +4 float row pad

    const int tid = threadIdx.x;
    const int o   = tid & 15;
    const int ln  = tid >> 4;

    // epilogue constants: load early, overlaps staging
    const float beta_o = beta[o];
    const float ab_o   = alpha[o] + bias[o];

    // ---- stage params (o2 in low bits: 16B-apart LDS writes = free 2-way) --
    {
        const int o2 = tid & 15, i2 = tid >> 4;
        const int pidx = o2 * 16 + i2;                    // [o2][i2] entry
        const float4 q = ((const float4*)quats)[pidx];
        const float sc = scale[pidx];
        const float qn2 = q.x*q.x + q.y*q.y + q.z*q.z + q.w*q.w;
        const float f = sc * rsq_fast(qn2 + EPSQ);
        qs[i2][o2][0] = q.x * f;
        qs[i2][o2][1] = q.y * f;
        qs[i2][o2][2] = q.z * f;
        qs[i2][o2][3] = q.w * f;
        tr[i2][o2][0] = 0.0f;
        tr[i2][o2][1] = trans[pidx*3 + 0];
        tr[i2][o2][2] = trans[pidx*3 + 1];
        tr[i2][o2][3] = trans[pidx*3 + 2];
    }
    // ---- stage x tile: 1024 contiguous floats, one float4 per thread ----
    {
        const float4 xv = ((const float4*)x)[(size_t)blockIdx.x * 256 + tid];
        *(float4*)&xs[tid >> 4][(tid & 15) * 4] = xv;
    }
    __syncthreads();

    // ---- votes[i] = (scale*qn) (x) x[n,i] + trans: 8 pk_fma each ----
    f2 vwx[16], vyz[16];
    #pragma unroll
    for (int i = 0; i < 16; ++i) {
        const f4 q4 = *(const f4*)&qs[i][o][0];
        const f4 t4 = *(const f4*)&tr[i][o][0];
        const f4 x4 = *(const f4*)&xs[ln][i * 4];
        hamilton_pk(q4.lo, q4.hi, x4.lo, x4.hi, t4.lo, t4.hi, vwx[i], vyz[i]);
    }

    // Running log2-domain logit generator: b_i = dot(vl, votes_i).
    f2 vlwx, vlyz, v0wx, v0yz;

    // ---- routing iter 0: b==0 -> uniform c=1/16, folded into squash ----
    {
        f2 uwxA = f2{0.f,0.f}, uwxB = f2{0.f,0.f};
        f2 uyzA = f2{0.f,0.f}, uyzB = f2{0.f,0.f};
        #pragma unroll
        for (int i = 0; i < 16; i += 2) {
            uwxA += vwx[i];   uyzA += vyz[i];
            uwxB += vwx[i+1]; uyzB += vyz[i+1];
        }
        const f2 uwx = uwxA + uwxB, uyz = uyzA + uyzB;
        f2 d = uwx * uwx;
        d = pk_fma(uyz, uyz, d);
        const float n2 = (d.x + d.y) * (1.0f / 256.0f);
        const float fq = n2 * rcp_fast(1.f + n2) * rsq_fast(n2 + EPSQ) * 0.0625f;
        v0wx = uwx * fq; v0yz = uyz * fq;
        vlwx = v0wx * LOG2E; vlyz = v0yz * LOG2E;
    }

    // ---- routing iters 1..2: PHASE-SPLIT for 16-wide ILP per phase.
    // Phase 1: all dots; 2: all exp2; 3: all 4-DPP reduces; 4: rcp+accum.
    // Each phase is 16 independent ops -> latency of trans/DPP chains is
    // covered by neighboring i's instead of relying on other waves.
    f2 s_wx, s_yz, vowx, voyz;
    #pragma unroll
    for (int it = 1; it < 3; ++it) {
        float e[16], se[16];
        #pragma unroll
        for (int i = 0; i < 16; ++i) {            // phase 1+2: dot -> exp2
            f2 d2 = vlwx * vwx[i];
            d2 = pk_fma(vlyz, vyz[i], d2);
            e[i] = __builtin_amdgcn_exp2f(d2.x + d2.y);
        }
        #pragma unroll
        for (int i = 0; i < 16; ++i)              // phase 3: 16 indep reduces
            se[i] = allsum16(e[i]);
        f2 snwxA = f2{0.f,0.f}, snwxB = f2{0.f,0.f};
        f2 snyzA = f2{0.f,0.f}, snyzB = f2{0.f,0.f};
        #pragma unroll
        for (int i = 0; i < 16; i += 2) {         // phase 4: rcp + accumulate
            const float cA = e[i]   * rcp_fast(se[i]);
            const float cB = e[i+1] * rcp_fast(se[i+1]);
            snwxA = pk_fma(f2{cA, cA}, vwx[i],   snwxA);
            snyzA = pk_fma(f2{cA, cA}, vyz[i],   snyzA);
            snwxB = pk_fma(f2{cB, cB}, vwx[i+1], snwxB);
            snyzB = pk_fma(f2{cB, cB}, vyz[i+1], snyzB);
        }
        const f2 snwx = snwxA + snwxB, snyz = snyzA + snyzB;
        s_wx = snwx; s_yz = snyz;
        const float n2 = snwx.x*snwx.x + snwx.y*snwx.y + snyz.x*snyz.x + snyz.y*snyz.y;
        const float fq = n2 * rcp_fast(1.f + n2) * rsq_fast(n2 + EPSQ);
        vowx = snwx * fq; voyz = snyz * fq;
        if (it == 1) {   // generator for iter 2: log2e * (v0 + v1)
            vlwx = (v0wx + vowx) * LOG2E;
            vlyz = (v0yz + voyz) * LOG2E;
        }
    }

    // ---- activation + store (coalesced float4 per thread) ----
    const float n2f = s_wx.x*s_wx.x + s_wx.y*s_wx.y + s_yz.x*s_yz.x + s_yz.y*s_yz.y;
    const float norm_s = sqrtf(n2f + EPSQ);
    const float tgt = beta_o * norm_s + ab_o;
    const float aAct = rcp_fast(1.f + __builtin_amdgcn_exp2f(-tgt * LOG2E));
    float4 ov;
    ov.x = vowx.x * aAct; ov.y = vowx.y * aAct;
    ov.z = voyz.x * aAct; ov.w = voyz.y * aAct;
    ((float4*)out)[(size_t)blockIdx.x * 256 + tid] = ov;
}

extern "C" void kernel_launch(void* const* d_in, const int* in_sizes, int n_in,
                              void* d_out, int out_size, void* d_ws, size_t ws_size,
                              hipStream_t stream) {
    const float* x     = (const float*)d_in[0];
    const float* quats = (const float*)d_in[1];
    const float* scale = (const float*)d_in[2];
    const float* trans = (const float*)d_in[3];
    const float* bias  = (const float*)d_in[4];
    const float* beta  = (const float*)d_in[5];
    const float* alpha = (const float*)d_in[6];
    float* out = (float*)d_out;

    const int N = in_sizes[0] / 64;      // x is [N,16,4]
    caps_kernel<<<N / 16, 256, 0, stream>>>(x, quats, scale, trans, bias, beta, alpha, out);
}

// Round 12
// 97.431 us; speedup vs baseline: 1.0171x; 1.0171x over previous
//
#include <hip/hip_runtime.h>
#include <math.h>

#define EPSQ 1e-8f
#define LOG2E 1.4426950408889634f

typedef float f2 __attribute__((ext_vector_type(2)));
typedef float f4 __attribute__((ext_vector_type(4)));

__device__ __forceinline__ float rcp_fast(float x) { return __builtin_amdgcn_rcpf(x); }
__device__ __forceinline__ float rsq_fast(float x) { return __builtin_amdgcn_rsqf(x); }
__device__ __forceinline__ f2 pk_fma(f2 a, f2 b, f2 c) { return __builtin_elementwise_fma(a, b, c); }

// DPP cross-lane move: ctrl must be a compile-time constant.
// NOTE: must stay as the builtin (NOT inline asm) — the compiler both fuses
// this into v_add_f32_dpp (GCNDPPCombine) and inserts the mandatory 2-cycle
// VALU->DPP hazard nops. Hand-asm without s_nop between chained DPP adds
// reads stale VGPRs (R11 failure: absmax 0.95).
#define DPP_F(x, ctrl) \
    __int_as_float(__builtin_amdgcn_update_dpp(0, __float_as_int(x), (ctrl), 0xF, 0xF, true))

// All-reduce sum within each aligned 16-lane group (pure VALU, no LDS).
__device__ __forceinline__ float allsum16(float v) {
    v += DPP_F(v, 0xB1);   // quad_perm [1,0,3,2]  == xor 1
    v += DPP_F(v, 0x4E);   // quad_perm [2,3,0,1]  == xor 2
    v += DPP_F(v, 0x124);  // row_ror:4
    v += DPP_F(v, 0x128);  // row_ror:8
    return v;
}

// Hamilton product (q * x) + t as EXACTLY 8 v_pk_fma_f32 (proven clean in R9).
__device__ __forceinline__ void hamilton_pk(f2 q01, f2 q23, f2 p01, f2 p23,
                                            f2 ta, f2 tb, f2& a, f2& b2) {
    asm("v_pk_fma_f32 %0, %2, %3, %4 op_sel:[0,0,0] op_sel_hi:[0,1,1]\n\t"
        "v_pk_fma_f32 %0, %2, %3, %0 op_sel:[1,1,0] op_sel_hi:[1,0,1] neg_lo:[1,0,0]\n\t"
        "v_pk_fma_f32 %0, %5, %6, %0 op_sel:[0,0,0] op_sel_hi:[0,1,1] neg_lo:[1,0,0]\n\t"
        "v_pk_fma_f32 %0, %5, %6, %0 op_sel:[1,1,0] op_sel_hi:[1,0,1] neg_lo:[1,0,0] neg_hi:[1,0,0]\n\t"
        "v_pk_fma_f32 %1, %2, %6, %7 op_sel:[0,0,0] op_sel_hi:[0,1,1]\n\t"
        "v_pk_fma_f32 %1, %2, %6, %1 op_sel:[1,1,0] op_sel_hi:[1,0,1] neg_lo:[1,0,0]\n\t"
        "v_pk_fma_f32 %1, %5, %3, %1 op_sel:[0,0,0] op_sel_hi:[0,1,1] neg_hi:[1,0,0]\n\t"
        "v_pk_fma_f32 %1, %5, %3, %1 op_sel:[1,1,0] op_sel_hi:[1,0,1]"
        : "=&v"(a), "=&v"(b2)
        : "v"(q01), "v"(p01), "v"(ta), "v"(q23), "v"(p23), "v"(tb));
}

// One thread per (sample n, output capsule o). Block = 256 = 16 samples x 16 o.
// tid = ln*16 + o (o in low 4 bits): softmax-over-o lives in one 16-lane DPP row.
// LDS holds ONLY the folded param tables (32 reads/thread); x is read straight
// from global with group-broadcast float4 loads (vmem/L1 pipe, mostly idle)
// -- offloads 1/3 of the CU-serialized LDS pipe traffic and removes the
// x-staging barrier dependency.
__global__ __launch_bounds__(256, 4) void caps_kernel(
    const float* __restrict__ x,      // [N,16,4]
    const float* __restrict__ quats,  // [16,16,4]
    const float* __restrict__ scale,  // [16,16,1]
    const float* __restrict__ trans,  // [16,16,3]
    const float* __restrict__ bias,   // [16]
    const float* __restrict__ beta,   // [16]
    const float* __restrict__ alpha,  // [16]
    float* __restrict__ out)          // [N,16,4]
{
    __shared__ __align__(16) float qs[16][16][4];  // folded scale * qn  [i][o][4]
    __shared__ __align__(16) float tr[16][16][4];  // (0, tx, ty, tz)    [i][o][4]

    const int tid = threadIdx.x;
    const int o   = tid & 15;
    const int ln  = tid >> 4;

    // epilogue constants: load early, overlaps staging
    const float beta_o = beta[o];
    const float ab_o   = alpha[o] + bias[o];

    // ---- stage params (o2 in low bits: 16B-apart LDS writes = free 2-way) --
    {
        const int o2 = tid & 15, i2 = tid >> 4;
        const int pidx = o2 * 16 + i2;                    // [o2][i2] entry
        const float4 q = ((const float4*)quats)[pidx];
        const float sc = scale[pidx];
        const float qn2 = q.x*q.x + q.y*q.y + q.z*q.z + q.w*q.w;
        const float f = sc * rsq_fast(qn2 + EPSQ);
        qs[i2][o2][0] = q.x * f;
        qs[i2][o2][1] = q.y * f;
        qs[i2][o2][2] = q.z * f;
        qs[i2][o2][3] = q.w * f;
        tr[i2][o2][0] = 0.0f;
        tr[i2][o2][1] = trans[pidx*3 + 0];
        tr[i2][o2][2] = trans[pidx*3 + 1];
        tr[i2][o2][3] = trans[pidx*3 + 2];
    }
    __syncthreads();

    // ---- votes[i] = (scale*qn) (x) x[n,i] + trans: 8 pk_fma each.
    // x4 comes from GLOBAL (16 lanes same address -> broadcast transaction).
    const f4* __restrict__ xg =
        (const f4*)x + ((size_t)blockIdx.x * 16 + ln) * 16;
    f2 vwx[16], vyz[16];
    #pragma unroll
    for (int i = 0; i < 16; ++i) {
        const f4 q4 = *(const f4*)&qs[i][o][0];
        const f4 t4 = *(const f4*)&tr[i][o][0];
        const f4 x4 = xg[i];
        hamilton_pk(q4.lo, q4.hi, x4.lo, x4.hi, t4.lo, t4.hi, vwx[i], vyz[i]);
    }

    // Running log2-domain logit generator: b_i = dot(vl, votes_i).
    f2 vlwx, vlyz, v0wx, v0yz;

    // ---- routing iter 0: b==0 -> uniform c=1/16, folded into squash ----
    {
        f2 uwx = f2{0.f, 0.f}, uyz = f2{0.f, 0.f};
        #pragma unroll
        for (int i = 0; i < 16; ++i) { uwx += vwx[i]; uyz += vyz[i]; }
        f2 d = uwx * uwx;
        d = pk_fma(uyz, uyz, d);
        const float n2 = (d.x + d.y) * (1.0f / 256.0f);
        const float fq = n2 * rcp_fast(1.f + n2) * rsq_fast(n2 + EPSQ) * 0.0625f;
        v0wx = uwx * fq; v0yz = uyz * fq;
        vlwx = v0wx * LOG2E; vlyz = v0yz * LOG2E;
    }

    // ---- routing iters 1..2: softmax over o via DPP all-reduce.
    // Max-subtraction dropped: |b_log2| bounded -> exp2 never overflows fp32.
    f2 s_wx, s_yz, vowx, voyz;
    #pragma unroll
    for (int it = 1; it < 3; ++it) {
        f2 snwx = f2{0.f, 0.f}, snyz = f2{0.f, 0.f};
        #pragma unroll
        for (int i = 0; i < 16; ++i) {
            f2 d2 = vlwx * vwx[i];
            d2 = pk_fma(vlyz, vyz[i], d2);
            const float e  = __builtin_amdgcn_exp2f(d2.x + d2.y);
            const float se = allsum16(e);
            const float c  = e * rcp_fast(se);
            snwx = pk_fma(f2{c, c}, vwx[i], snwx);
            snyz = pk_fma(f2{c, c}, vyz[i], snyz);
        }
        s_wx = snwx; s_yz = snyz;
        const float n2 = snwx.x*snwx.x + snwx.y*snwx.y + snyz.x*snyz.x + snyz.y*snyz.y;
        const float fq = n2 * rcp_fast(1.f + n2) * rsq_fast(n2 + EPSQ);
        vowx = snwx * fq; voyz = snyz * fq;
        if (it == 1) {   // generator for iter 2: log2e * (v0 + v1)
            vlwx = (v0wx + vowx) * LOG2E;
            vlyz = (v0yz + voyz) * LOG2E;
        }
    }

    // ---- activation + store (coalesced float4 per thread) ----
    const float n2f = s_wx.x*s_wx.x + s_wx.y*s_wx.y + s_yz.x*s_yz.x + s_yz.y*s_yz.y;
    const float norm_s = sqrtf(n2f + EPSQ);
    const float tgt = beta_o * norm_s + ab_o;
    const float aAct = rcp_fast(1.f + __builtin_amdgcn_exp2f(-tgt * LOG2E));
    float4 ov;
    ov.x = vowx.x * aAct; ov.y = vowx.y * aAct;
    ov.z = voyz.x * aAct; ov.w = voyz.y * aAct;
    ((float4*)out)[(size_t)blockIdx.x * 256 + tid] = ov;
}

extern "C" void kernel_launch(void* const* d_in, const int* in_sizes, int n_in,
                              void* d_out, int out_size, void* d_ws, size_t ws_size,
                              hipStream_t stream) {
    const float* x     = (const float*)d_in[0];
    const float* quats = (const float*)d_in[1];
    const float* scale = (const float*)d_in[2];
    const float* trans = (const float*)d_in[3];
    const float* bias  = (const float*)d_in[4];
    const float* beta  = (const float*)d_in[5];
    const float* alpha = (const float*)d_in[6];
    float* out = (float*)d_out;

    const int N = in_sizes[0] / 64;      // x is [N,16,4]
    caps_kernel<<<N / 16, 256, 0, stream>>>(x, quats, scale, trans, bias, beta, alpha, out);
}